// Round 1
// baseline (108.554 us; speedup 1.0000x reference)
//
#include <hip/hip_runtime.h>
#include <math.h>

#define BB 2
#define HH 256
#define WW 832
#define HWIMG (HH * WW)

#define TS 32              // output tile is 32x32, 1 px/thread
#define TXN (WW / TS)      // 26
#define TYN (HH / TS)      // 8
#define RG 52              // keeper-detection region: TS + 2*10 halo
#define RGPX (RG * RG)     // 2704
#define KCAP 256           // keeper/entry capacity (expect ~30, 8.7x headroom)

// ---------------------------------------------------------------------------
// Orientation at (i,j): 3x3 wrap box-blur (jnp.roll) -> jnp.gradient
// (one-sided at borders) -> atan2. Box sums of 0/1 exact in fp32; all 25
// loads independent -> one memory round trip. Bit-identical to dense pass.
// ---------------------------------------------------------------------------
__device__ inline float theta_at(const float* __restrict__ m, int i, int j) {
    int ri[5], cj[5];
#pragma unroll
    for (int t = 0; t < 5; ++t) {
        int r = i + t - 2; r = (r < 0) ? r + HH : (r >= HH ? r - HH : r);
        int c = j + t - 2; c = (c < 0) ? c + WW : (c >= WW ? c - WW : c);
        ri[t] = r * WW; cj[t] = c;
    }
    float S[5][5];
#pragma unroll
    for (int a = 0; a < 5; ++a)
#pragma unroll
        for (int c = 0; c < 5; ++c)
            S[a][c] = m[ri[a] + cj[c]];
    float ct[5], cm[5], cb[5];
#pragma unroll
    for (int c = 0; c < 5; ++c) {
        ct[c] = S[0][c] + S[1][c] + S[2][c];
        cm[c] = S[1][c] + S[2][c] + S[3][c];
        cb[c] = S[2][c] + S[3][c] + S[4][c];
    }
    float Bm = ct[1] + ct[2] + ct[3];
    float Bp = cb[1] + cb[2] + cb[3];
    float Bl = cm[0] + cm[1] + cm[2];
    float Br = cm[2] + cm[3] + cm[4];
    float Bc = cm[1] + cm[2] + cm[3];
    float gy = (i == 0) ? (Bp - Bc) : (i == HH - 1) ? (Bc - Bm) : 0.5f * (Bp - Bm);
    float gx = (j == 0) ? (Br - Bc) : (j == WW - 1) ? (Bc - Bl) : 0.5f * (Br - Bl);
    return atan2f(gy, gx);
}

// ---------------------------------------------------------------------------
// Fused kernel: one block per 32x32 output tile, 1024 threads (16 waves).
// Each block recomputes keepers over its 52x52 halo region (2.6x redundancy)
// so there is NO cross-block communication: detection -> wave-per-keeper
// search -> in-LDS entry list -> per-pixel diffusion, all in one dispatch.
// No workspace, no global intermediates.
// ---------------------------------------------------------------------------
__global__ __launch_bounds__(1024) void fused_kernel(
        const float* __restrict__ src, const float* __restrict__ dst,
        const int* __restrict__ xx, const int* __restrict__ yy, int K,
        float* __restrict__ out) {
    __shared__ int kox[128], koy[128];
    __shared__ float kd[128];
    __shared__ int recs[KCAP];
    __shared__ float tss[KCAP];
    __shared__ float4 ent[KCAP];
    __shared__ float wt[441];
    __shared__ int nkeep, ne;

    int tid = threadIdx.x;
    if (tid == 0) { nkeep = 0; ne = 0; }
    for (int t = tid; t < K; t += 1024) {
        int ox = xx[t], oy = yy[t];
        kox[t] = ox; koy[t] = oy;
        kd[t] = 20.0f * sqrtf((float)(ox * ox + oy * oy));
    }
    for (int t = tid; t < 441; t += 1024) {
        int dy = t / 21 - 10;
        int dx = t % 21 - 10;
        wt[t] = expf(-sqrtf((float)(dx * dx + dy * dy)) / 5.0f);
    }

    int b = blockIdx.z;
    int i0 = blockIdx.y * TS;
    int j0 = blockIdx.x * TS;
    const float* sb = src + b * HWIMG;
    const float* db = dst + b * HWIMG;
    __syncthreads();

    // ---- Phase 1: keeper detection over the 52x52 halo region ----
    for (int t = tid; t < RGPX; t += 1024) {
        int gi = i0 - 10 + t / RG;
        int gj = j0 - 10 + t % RG;
        if (gi < 0 || gi >= HH || gj < 0 || gj >= WW) continue;
        if (sb[gi * WW + gj] > 0.5f) {
            // smaller-lin-index nbrs: rows -2,-1 (dj -2..2), row 0 (dj -2,-1)
            float m = 0.f;
#pragma unroll
            for (int p = 0; p < 12; ++p) {
                int di = (p < 5) ? -2 : (p < 10 ? -1 : 0);
                int dj = (p < 5) ? (p - 2) : (p < 10 ? (p - 7) : (p - 12));
                int ii = gi + di, jj = gj + dj;
                bool inb = (ii >= 0) && (jj >= 0) && (jj < WW);
                float v = sb[inb ? (ii * WW + jj) : 0];
                m = fmaxf(m, inb ? v : 0.f);
            }
            if (m <= 0.5f) {
                float ts = theta_at(sb, gi, gj);
                int pos = atomicAdd(&nkeep, 1);      // LDS atomic
                if (pos < KCAP) { recs[pos] = gj | (gi << 10); tss[pos] = ts; }
            }
        }
    }
    __syncthreads();

    // ---- Phase 2: wave-per-keeper 105-offset search (lex (score,k) argmin) ----
    int nk = (nkeep < KCAP) ? nkeep : KCAP;
    int lane = tid & 63;
    int wv = tid >> 6;
    for (int w = wv; w < nk; w += 16) {
        int rec = recs[w];
        int kj = rec & 1023;
        int ki = rec >> 10;
        float ts = tss[w];

        float best = 1e9f;
        int bk = 1 << 20;
#pragma unroll
        for (int rr = 0; rr < 2; ++rr) {
            int k = lane + rr * 64;
            if (k < K) {
                int pi = ki + koy[k], pj = kj + kox[k];
                if (pi >= 0 && pi < HH && pj >= 0 && pj < WW && db[pi * WW + pj] > 0.5f) {
                    float td = theta_at(db, pi, pj);   // ~2 active lanes/wave
                    float sc = kd[k] + 10.5f * (1.0f - cosf(ts - td));
                    if (sc < best || (sc == best && k < bk)) { best = sc; bk = k; }
                }
            }
        }
#pragma unroll
        for (int off = 32; off >= 1; off >>= 1) {
            float ob = __shfl_down(best, off, 64);
            int ok = __shfl_down(bk, off, 64);
            if (ob < best || (ob == best && ok < bk)) { best = ob; bk = ok; }
        }
        if (lane == 0 && best < 5e8f) {
            int pos = atomicAdd(&ne, 1);             // LDS atomic
            if (pos < KCAP)
                ent[pos] = make_float4((float)kj, (float)ki,
                                       (float)kox[bk], (float)koy[bk]);
        }
    }
    __syncthreads();

    // ---- Phase 3: 21x21 weighted diffusion, 1 px/thread ----
    int nn = (ne < KCAP) ? ne : KCAP;
    int gj = j0 + (tid & 31);
    int gi = i0 + (tid >> 5);
    float nx = 0.f, ny = 0.f, de = 0.f;
    for (int c = 0; c < nn; ++c) {
        float4 E = ent[c];                           // broadcast LDS read
        int dj = (int)E.x - gj;
        int di = (int)E.y - gi;
        if (dj >= -10 && dj <= 10 && di >= -10 && di <= 10) {
            float w = wt[(di + 10) * 21 + dj + 10];
            de += w; nx += w * E.z; ny += w * E.w;
        }
    }
    float inv = 0.6f / (de + 1e-6f);
    int obase = b * 2 * HWIMG;
    out[obase + gi * WW + gj] = (float)gj + nx * inv;
    out[obase + HWIMG + gi * WW + gj] = (float)gi + ny * inv;
}

// ---------------------------------------------------------------------------
extern "C" void kernel_launch(void* const* d_in, const int* in_sizes, int n_in,
                              void* d_out, int out_size, void* d_ws, size_t ws_size,
                              hipStream_t stream) {
    const float* src = (const float*)d_in[0];
    const float* dst = (const float*)d_in[1];
    const int* xx = (const int*)d_in[2];
    const int* yy = (const int*)d_in[3];
    int K = in_sizes[2];  // 105

    float* out = (float*)d_out;
    dim3 grid(TXN, TYN, BB);
    fused_kernel<<<grid, dim3(1024), 0, stream>>>(src, dst, xx, yy, K, out);
}

// Round 2
// 99.156 us; speedup vs baseline: 1.0948x; 1.0948x over previous
//
#include <hip/hip_runtime.h>
#include <math.h>

#define BB 2
#define HH 256
#define WW 832
#define HWIMG (HH * WW)

#define TS 32              // output tile is 32x32, 1 px/thread
#define TXN (WW / TS)      // 26
#define TYN (HH / TS)      // 8
#define KCAP 256           // keeper/entry capacity (expect ~30, 8x headroom)

// Staged LDS regions (per block):
//   src: keeper rows [i0-10, i0+41] need nbr di in [-2,0], dj in [-2,2] and
//        theta ring +-2  -> origin (i0-12, j0-12), 56 x 56
//   dst: search px rows [i0-13, i0+44], cols [j0-17, j0+48], theta ring +-2,
//        col origin rounded to float4 -> origin (i0-15, j0-20), 62 x 72
#define SRH 56
#define SRW 56
#define DRH 62
#define DRW 72

// ---------------------------------------------------------------------------
// Orientation at (i,j), GLOBAL memory, full wrap (jnp.roll) + one-sided
// border gradients. Used only for image-border pixels (rare).
// ---------------------------------------------------------------------------
__device__ inline float theta_at(const float* __restrict__ m, int i, int j) {
    int ri[5], cj[5];
#pragma unroll
    for (int t = 0; t < 5; ++t) {
        int r = i + t - 2; r = (r < 0) ? r + HH : (r >= HH ? r - HH : r);
        int c = j + t - 2; c = (c < 0) ? c + WW : (c >= WW ? c - WW : c);
        ri[t] = r * WW; cj[t] = c;
    }
    float S[5][5];
#pragma unroll
    for (int a = 0; a < 5; ++a)
#pragma unroll
        for (int c = 0; c < 5; ++c)
            S[a][c] = m[ri[a] + cj[c]];
    float ct[5], cm[5], cb[5];
#pragma unroll
    for (int c = 0; c < 5; ++c) {
        ct[c] = S[0][c] + S[1][c] + S[2][c];
        cm[c] = S[1][c] + S[2][c] + S[3][c];
        cb[c] = S[2][c] + S[3][c] + S[4][c];
    }
    float Bm = ct[1] + ct[2] + ct[3];
    float Bp = cb[1] + cb[2] + cb[3];
    float Bl = cm[0] + cm[1] + cm[2];
    float Br = cm[2] + cm[3] + cm[4];
    float Bc = cm[1] + cm[2] + cm[3];
    float gy = (i == 0) ? (Bp - Bc) : (i == HH - 1) ? (Bc - Bm) : 0.5f * (Bp - Bm);
    float gx = (j == 0) ? (Br - Bc) : (j == WW - 1) ? (Bc - Bl) : 0.5f * (Br - Bl);
    return atan2f(gy, gx);
}

// ---------------------------------------------------------------------------
// Orientation from the STAGED LDS region, interior pixels only (>=2 px from
// the image border): no wrap can trigger, gradients are purely central, and
// the staged values are exact copies -> bit-identical to theta_at.
// ---------------------------------------------------------------------------
__device__ inline float theta_lds(const float* __restrict__ m, int stride,
                                  int li, int lj) {
    const float* p = m + (li - 2) * stride + (lj - 2);
    float S[5][5];
#pragma unroll
    for (int a = 0; a < 5; ++a)
#pragma unroll
        for (int c = 0; c < 5; ++c)
            S[a][c] = p[a * stride + c];
    float ct[5], cm[5], cb[5];
#pragma unroll
    for (int c = 0; c < 5; ++c) {
        ct[c] = S[0][c] + S[1][c] + S[2][c];
        cm[c] = S[1][c] + S[2][c] + S[3][c];
        cb[c] = S[2][c] + S[3][c] + S[4][c];
    }
    float Bm = ct[1] + ct[2] + ct[3];
    float Bp = cb[1] + cb[2] + cb[3];
    float Bl = cm[0] + cm[1] + cm[2];
    float Br = cm[2] + cm[3] + cm[4];
    float gy = 0.5f * (Bp - Bm);
    float gx = 0.5f * (Br - Bl);
    return atan2f(gy, gx);
}

// Guarded float4 load: out-of-image components read as 0 (matches the
// reference's zero-fill gather semantics). Vector path for the common
// fully-in-image case; component path only at image edges.
__device__ inline float4 load4_guard(const float* __restrict__ img, int r, int c0) {
    float4 v = make_float4(0.f, 0.f, 0.f, 0.f);
    if (r >= 0 && r < HH) {
        if (c0 >= 0 && c0 + 3 < WW) {
            v = *(const float4*)(img + r * WW + c0);
        } else {
            const float* rp = img + r * WW;
            if (c0 + 0 >= 0 && c0 + 0 < WW) v.x = rp[c0 + 0];
            if (c0 + 1 >= 0 && c0 + 1 < WW) v.y = rp[c0 + 1];
            if (c0 + 2 >= 0 && c0 + 2 < WW) v.z = rp[c0 + 2];
            if (c0 + 3 >= 0 && c0 + 3 < WW) v.w = rp[c0 + 3];
        }
    }
    return v;
}

// ---------------------------------------------------------------------------
// Fused kernel: one block per 32x32 output tile, 1024 threads (16 waves).
// Stage src/dst halo regions into LDS with bulk float4 loads (all issued
// up-front -> one cold-HBM latency round instead of serialized scattered
// misses; caches are wiped between iterations by the harness poison fill),
// then detection -> wave-per-keeper search -> diffusion entirely from LDS.
// ---------------------------------------------------------------------------
__global__ __launch_bounds__(1024) void fused_kernel(
        const float* __restrict__ src, const float* __restrict__ dst,
        const int* __restrict__ xx, const int* __restrict__ yy, int K,
        float* __restrict__ out) {
    __shared__ float4 slds4[SRH * SRW / 4];   // 784  (12.5 KB)
    __shared__ float4 dlds4[DRH * DRW / 4];   // 1116 (17.9 KB)
    __shared__ int kox[128], koy[128];
    __shared__ float kd[128];
    __shared__ int recs[KCAP];
    __shared__ float tss[KCAP];
    __shared__ float4 ent[KCAP];
    __shared__ float wt[441];
    __shared__ int nkeep, ne;
    float* slds = (float*)slds4;
    float* dlds = (float*)dlds4;

    int tid = threadIdx.x;
    int b = blockIdx.z;
    int i0 = blockIdx.y * TS;
    int j0 = blockIdx.x * TS;
    const float* sb = src + b * HWIMG;
    const float* db = dst + b * HWIMG;

    if (tid == 0) { nkeep = 0; ne = 0; }

    // ---- Bulk staging: all global loads independent, issued together ----
#pragma unroll
    for (int t = tid; t < SRH * (SRW / 4); t += 1024)       // 784: 1 round
        slds4[t] = load4_guard(sb, (i0 - 12) + t / (SRW / 4),
                               (j0 - 12) + (t % (SRW / 4)) * 4);
    for (int t = tid; t < DRH * (DRW / 4); t += 1024)       // 1116: 2 rounds
        dlds4[t] = load4_guard(db, (i0 - 15) + t / (DRW / 4),
                               (j0 - 20) + (t % (DRW / 4)) * 4);

    for (int t = tid; t < K; t += 1024) {
        int ox = xx[t], oy = yy[t];
        kox[t] = ox; koy[t] = oy;
        kd[t] = 20.0f * sqrtf((float)(ox * ox + oy * oy));
    }
    for (int t = tid; t < 441; t += 1024) {
        int dy = t / 21 - 10;
        int dx = t % 21 - 10;
        wt[t] = expf(-sqrtf((float)(dx * dx + dy * dy)) / 5.0f);
    }
    __syncthreads();

    // ---- Phase 1: keeper detection over the 52x52 halo region (LDS) ----
    for (int t = tid; t < 52 * 52; t += 1024) {
        int rl = t / 52, cl = t % 52;
        int li = rl + 2, lj = cl + 2;         // region coords (origin i0-12,j0-12)
        if (slds[li * SRW + lj] > 0.5f) {     // out-of-image staged as 0
            // smaller-lin-index nbrs: rows -2,-1 (dj -2..2), row 0 (dj -2,-1)
            float m = 0.f;
#pragma unroll
            for (int p = 0; p < 12; ++p) {
                int di = (p < 5) ? -2 : (p < 10 ? -1 : 0);
                int dj = (p < 5) ? (p - 2) : (p < 10 ? (p - 7) : (p - 12));
                m = fmaxf(m, slds[(li + di) * SRW + (lj + dj)]);
            }
            if (m <= 0.5f) {
                int gi = i0 - 10 + rl, gj = j0 - 10 + cl;
                bool inner = (gi >= 2) && (gi < HH - 2) && (gj >= 2) && (gj < WW - 2);
                float ts = inner ? theta_lds(slds, SRW, li, lj)
                                 : theta_at(sb, gi, gj);
                int pos = atomicAdd(&nkeep, 1);          // LDS atomic
                if (pos < KCAP) { recs[pos] = gj | (gi << 10); tss[pos] = ts; }
            }
        }
    }
    __syncthreads();

    // ---- Phase 2: wave-per-keeper 105-offset search (lex (score,k) argmin) ----
    int nk = (nkeep < KCAP) ? nkeep : KCAP;
    int lane = tid & 63;
    int wv = tid >> 6;
    for (int w = wv; w < nk; w += 16) {
        int rec = recs[w];
        int kj = rec & 1023;
        int ki = rec >> 10;
        float ts = tss[w];
        int kli = ki - i0 + 15;               // dst-region coords (origin i0-15,j0-20)
        int klj = kj - j0 + 20;

        float best = 1e9f;
        int bk = 1 << 20;
#pragma unroll
        for (int rr = 0; rr < 2; ++rr) {
            int k = lane + rr * 64;
            if (k < K) {
                int pli = kli + koy[k], plj = klj + kox[k];
                if (dlds[pli * DRW + plj] > 0.5f) {      // OOB staged as 0
                    int pi = ki + koy[k], pj = kj + kox[k];
                    bool inner = (pi >= 2) && (pi < HH - 2) && (pj >= 2) && (pj < WW - 2);
                    float td = inner ? theta_lds(dlds, DRW, pli, plj)
                                     : theta_at(db, pi, pj);
                    float sc = kd[k] + 10.5f * (1.0f - cosf(ts - td));
                    if (sc < best || (sc == best && k < bk)) { best = sc; bk = k; }
                }
            }
        }
#pragma unroll
        for (int off = 32; off >= 1; off >>= 1) {
            float ob = __shfl_down(best, off, 64);
            int ok = __shfl_down(bk, off, 64);
            if (ob < best || (ob == best && ok < bk)) { best = ob; bk = ok; }
        }
        if (lane == 0 && best < 5e8f) {
            int pos = atomicAdd(&ne, 1);                 // LDS atomic
            if (pos < KCAP)
                ent[pos] = make_float4((float)kj, (float)ki,
                                       (float)kox[bk], (float)koy[bk]);
        }
    }
    __syncthreads();

    // ---- Phase 3: 21x21 weighted diffusion, 1 px/thread ----
    int nn = (ne < KCAP) ? ne : KCAP;
    int gj = j0 + (tid & 31);
    int gi = i0 + (tid >> 5);
    float nx = 0.f, ny = 0.f, de = 0.f;
    for (int c = 0; c < nn; ++c) {
        float4 E = ent[c];                               // broadcast LDS read
        int dj = (int)E.x - gj;
        int di = (int)E.y - gi;
        if (dj >= -10 && dj <= 10 && di >= -10 && di <= 10) {
            float w = wt[(di + 10) * 21 + dj + 10];
            de += w; nx += w * E.z; ny += w * E.w;
        }
    }
    float inv = 0.6f / (de + 1e-6f);
    int obase = b * 2 * HWIMG;
    out[obase + gi * WW + gj] = (float)gj + nx * inv;
    out[obase + HWIMG + gi * WW + gj] = (float)gi + ny * inv;
}

// ---------------------------------------------------------------------------
extern "C" void kernel_launch(void* const* d_in, const int* in_sizes, int n_in,
                              void* d_out, int out_size, void* d_ws, size_t ws_size,
                              hipStream_t stream) {
    const float* src = (const float*)d_in[0];
    const float* dst = (const float*)d_in[1];
    const int* xx = (const int*)d_in[2];
    const int* yy = (const int*)d_in[3];
    int K = in_sizes[2];  // 105

    float* out = (float*)d_out;
    dim3 grid(TXN, TYN, BB);
    fused_kernel<<<grid, dim3(1024), 0, stream>>>(src, dst, xx, yy, K, out);
}